// Round 6
// baseline (346.300 us; speedup 1.0000x reference)
//
#include <hip/hip_runtime.h>
#include <hip/hip_bf16.h>

typedef unsigned short u16;
typedef __attribute__((ext_vector_type(8))) short short8;  // 8 bf16 (4 VGPRs)
typedef __attribute__((ext_vector_type(4))) float f32x4;

#define BATCH 8
#define CH 256
#define NPIX 4096
#define KD 32   // C/8

static __device__ __forceinline__ u16 f2bf(float f) {
  union { __hip_bfloat16 h; u16 u; } cv;
  cv.h = __float2bfloat16(f);
  return cv.u;
}

// ---------------------------------------------------------------------------
// Kernel 1: projections. x [B][C][N] f32 -> fT/gT [B][N][32] bf16, hh [B][C][N] bf16
// ---------------------------------------------------------------------------
__global__ __launch_bounds__(256) void proj_kernel(
    const float* __restrict__ x,
    const float* __restrict__ Wf, const float* __restrict__ bfp,
    const float* __restrict__ Wg, const float* __restrict__ bgp,
    const float* __restrict__ Wh, const float* __restrict__ bhp,
    u16* __restrict__ fT, u16* __restrict__ gT, u16* __restrict__ hhb)
{
  __shared__ float xs[CH][36];
  const int b  = blockIdx.x >> 7;
  const int n0 = (blockIdx.x & 127) * 32;
  const int t  = threadIdx.x;

  const float* xb = x + ((size_t)b * CH) * NPIX + n0;
  #pragma unroll
  for (int kk = 0; kk < 8; ++kk) {
    int v = kk * 256 + t;
    int c = v >> 3, p4 = v & 7;
    float4 d = *(const float4*)(xb + (size_t)c * NPIX + p4 * 4);
    *(float4*)&xs[c][p4 * 4] = d;
  }
  __syncthreads();

  const int o = t;
  float acch[32];
  #pragma unroll
  for (int p = 0; p < 32; ++p) acch[p] = bhp[o];

  const int o2 = t & 63;
  const int oo = o2 & 31;
  const bool isf = o2 < 32;
  const float* Wfg = isf ? Wf : Wg;
  const float bias2 = isf ? bfp[oo] : bgp[oo];
  const int pg = (t >> 6) * 8;
  float accf[8];
  #pragma unroll
  for (int p = 0; p < 8; ++p) accf[p] = bias2;

  const float* whr  = Wh  + o * CH;
  const float* wfgr = Wfg + oo * CH;
  for (int c = 0; c < CH; c += 4) {
    float4 wh4 = *(const float4*)(whr + c);
    float4 wf4 = *(const float4*)(wfgr + c);
    float wha[4] = {wh4.x, wh4.y, wh4.z, wh4.w};
    float wfa[4] = {wf4.x, wf4.y, wf4.z, wf4.w};
    #pragma unroll
    for (int cc = 0; cc < 4; ++cc) {
      float wh = wha[cc], wf = wfa[cc];
      #pragma unroll
      for (int p4 = 0; p4 < 8; ++p4) {
        float4 xv = *(const float4*)&xs[c + cc][p4 * 4];
        acch[p4*4+0] = fmaf(wh, xv.x, acch[p4*4+0]);
        acch[p4*4+1] = fmaf(wh, xv.y, acch[p4*4+1]);
        acch[p4*4+2] = fmaf(wh, xv.z, acch[p4*4+2]);
        acch[p4*4+3] = fmaf(wh, xv.w, acch[p4*4+3]);
      }
      #pragma unroll
      for (int p = 0; p < 8; ++p) accf[p] = fmaf(wf, xs[c + cc][pg + p], accf[p]);
    }
  }

  u16* hrow = hhb + ((size_t)b * CH + o) * NPIX + n0;
  #pragma unroll
  for (int q = 0; q < 4; ++q) {
    uint4 u;
    u.x = f2bf(acch[q*8+0]) | ((unsigned)f2bf(acch[q*8+1]) << 16);
    u.y = f2bf(acch[q*8+2]) | ((unsigned)f2bf(acch[q*8+3]) << 16);
    u.z = f2bf(acch[q*8+4]) | ((unsigned)f2bf(acch[q*8+5]) << 16);
    u.w = f2bf(acch[q*8+6]) | ((unsigned)f2bf(acch[q*8+7]) << 16);
    *(uint4*)(hrow + q * 8) = u;
  }
  u16* dst = (isf ? fT : gT) + ((size_t)b * NPIX + n0 + pg) * KD + oo;
  #pragma unroll
  for (int p = 0; p < 8; ++p) dst[(size_t)p * KD] = f2bf(accf[p]);
}

// ---------------------------------------------------------------------------
// Kernel 2 (fused attn + PV), pipelined, register-dieted:
//  - launch_bounds(512,2): 256-VGPR ceiling -> no forced spills in main loop
//    (R5's (512,4) forced a 128 cap below the ~160 live set = loop spills).
//  - g(t+1) prefetch rides vmcnt across the barrier (named ping-pong regs);
//    hh frags loaded inside the chunk (L2-resident, XCD-pinned) -> -32 VGPRs.
//  - attention f32 stores non-temporal; only lgkmcnt drained at barriers.
// ---------------------------------------------------------------------------
__global__ __launch_bounds__(512, 2) void fused_attn_pv(
    const u16* __restrict__ fT, const u16* __restrict__ gT,
    const u16* __restrict__ hhb, const float* __restrict__ x,
    const float* __restrict__ gamma,
    float* __restrict__ attn_out, float* __restrict__ outp)
{
  __shared__ u16 Pt[2][64 * 64];    // ping-pong P^T tiles, 8KB each
  __shared__ float part[8][64];
  __shared__ float invs[64];

  const int bid = blockIdx.x;
  const int b  = bid & 7;            // round-robin XCD: batch <-> XCD
  const int n0 = (bid >> 3) * 64;    // i-stripe base
  const int t  = threadIdx.x;
  const int iw = t >> 6, l = t & 63;
  const int lg = l >> 4, lm = l & 15;

  const u16* fb = fT + ((size_t)b * NPIX + n0) * KD;
  const u16* gb = gT + (size_t)b * NPIX * KD;
  const u16* hb = hhb + (size_t)b * CH * NPIX;

  f32x4 z4 = {0.f, 0.f, 0.f, 0.f};

  short8 ff[4];
  #pragma unroll
  for (int it = 0; it < 4; ++it)
    ff[it] = *(const short8*)(fb + (it * 16 + lm) * KD + lg * 8);

  // ---- pass 1: rowsums of exp(s) ----
  float sum[4][4];
  #pragma unroll
  for (int it = 0; it < 4; ++it)
    #pragma unroll
    for (int r = 0; r < 4; ++r) sum[it][r] = 0.f;

  const int j1 = iw * 512;
  for (int jt = 0; jt < 32; ++jt) {
    int j0 = j1 + jt * 16;
    short8 gf = *(const short8*)(gb + (size_t)(j0 + lm) * KD + lg * 8);
    #pragma unroll
    for (int it = 0; it < 4; ++it) {
      f32x4 s = __builtin_amdgcn_mfma_f32_16x16x32_bf16(ff[it], gf, z4, 0, 0, 0);
      #pragma unroll
      for (int r = 0; r < 4; ++r) sum[it][r] += __expf(s[r]);
    }
  }
  #pragma unroll
  for (int m = 1; m < 16; m <<= 1)
    #pragma unroll
    for (int it = 0; it < 4; ++it)
      #pragma unroll
      for (int r = 0; r < 4; ++r) sum[it][r] += __shfl_xor(sum[it][r], m, 64);
  if (lm == 0) {
    #pragma unroll
    for (int it = 0; it < 4; ++it)
      #pragma unroll
      for (int r = 0; r < 4; ++r) part[iw][it * 16 + lg * 4 + r] = sum[it][r];
  }
  __syncthreads();
  if (t < 64) {
    float s = 0.f;
    #pragma unroll
    for (int w2 = 0; w2 < 8; ++w2) s += part[w2][t];
    invs[t] = 1.0f / s;
  }
  __syncthreads();

  // ---- pass 2 ----
  const int it2 = iw >> 1, jsub = iw & 1;
  float inv4[4];
  #pragma unroll
  for (int r = 0; r < 4; ++r) inv4[r] = invs[it2 * 16 + lg * 4 + r];
  const short8 f2 = ff[it2];

  float* arow = attn_out + ((size_t)b * NPIX + n0 + it2 * 16 + lg * 4) * NPIX;

  f32x4 acc[2][4];
  #pragma unroll
  for (int mf = 0; mf < 2; ++mf)
    #pragma unroll
    for (int nf = 0; nf < 4; ++nf) acc[mf][nf] = z4;

  short8 gP[2], gQ[2];

  auto LDG = [&](short8 (&g2)[2], int JC) {
    #pragma unroll
    for (int st = 0; st < 2; ++st)
      g2[st] = *(const short8*)(gb + (size_t)(JC + jsub * 32 + st * 16 + lm) * KD + lg * 8);
  };

  // one 64-j chunk: QK with gc, prefetch gn@JN, load hh frags (L2-hot),
  // softmax+stores, barrier (lgkm only), PV.
  auto HALF = [&](u16* buf, short8 (&gc)[2], short8 (&gn)[2], int JC, int JN) {
    f32x4 s[2];
    #pragma unroll
    for (int st = 0; st < 2; ++st)
      s[st] = __builtin_amdgcn_mfma_f32_16x16x32_bf16(f2, gc[st], z4, 0, 0, 0);
    LDG(gn, JN);                           // in flight across the barrier
    short8 hc[2][2];
    #pragma unroll
    for (int m = 0; m < 2; ++m)
      #pragma unroll
      for (int ks = 0; ks < 2; ++ks)
        hc[m][ks] = *(const short8*)(hb + (size_t)(iw * 32 + m * 16 + lm) * NPIX
                                     + JC + ks * 32 + lg * 8);
    #pragma unroll
    for (int st = 0; st < 2; ++st) {
      const int j0 = JC + jsub * 32 + st * 16;
      #pragma unroll
      for (int r = 0; r < 4; ++r) {
        float p = __expf(s[st][r]) * inv4[r];
        __builtin_nontemporal_store(p, arow + (size_t)r * NPIX + j0 + lm);
        int iloc = it2 * 16 + lg * 4 + r;
        int jloc = jsub * 32 + st * 16 + lm;
        int byte = iloc * 128 + ((jloc * 2) ^ (((lg * 4 + r) & 7) << 4));
        *(u16*)((char*)buf + byte) = f2bf(p);
      }
    }
    asm volatile("s_waitcnt lgkmcnt(0)\n\ts_barrier" ::: "memory");
    #pragma unroll
    for (int nf = 0; nf < 4; ++nf) {
      #pragma unroll
      for (int ks = 0; ks < 2; ++ks) {
        int byte = (nf * 16 + lm) * 128 + (((ks * 4 + lg) * 16) ^ ((lm & 7) << 4));
        short8 pf = *(const short8*)((char*)buf + byte);
        acc[0][nf] = __builtin_amdgcn_mfma_f32_16x16x32_bf16(hc[0][ks], pf, acc[0][nf], 0, 0, 0);
        acc[1][nf] = __builtin_amdgcn_mfma_f32_16x16x32_bf16(hc[1][ks], pf, acc[1][nf], 0, 0, 0);
      }
    }
  };

  LDG(gP, 0);
  for (int jc = 0; jc < NPIX; jc += 128) {
    int n1 = (jc + 64) & (NPIX - 1);
    int n2 = (jc + 128) & (NPIX - 1);   // wraps to 0 on last iter (harmless)
    HALF(&Pt[0][0], gP, gQ, jc, n1);
    HALF(&Pt[1][0], gQ, gP, jc + 64, n2);
  }

  // ---- epilogue ----
  const float gm = gamma[0];
  #pragma unroll
  for (int mf = 0; mf < 2; ++mf) {
    #pragma unroll
    for (int r = 0; r < 4; ++r) {
      int c = iw * 32 + mf * 16 + lg * 4 + r;
      #pragma unroll
      for (int nf = 0; nf < 4; ++nf) {
        int i = n0 + nf * 16 + lm;
        size_t idx = ((size_t)b * CH + c) * NPIX + i;
        outp[idx] = fmaf(gm, acc[mf][nf][r], x[idx]);
      }
    }
  }
}

// ---------------------------------------------------------------------------
extern "C" void kernel_launch(void* const* d_in, const int* in_sizes, int n_in,
                              void* d_out, int out_size, void* d_ws, size_t ws_size,
                              hipStream_t stream) {
  const float* x     = (const float*)d_in[0];
  const float* Wf    = (const float*)d_in[1];
  const float* bf    = (const float*)d_in[2];
  const float* Wg    = (const float*)d_in[3];
  const float* bg    = (const float*)d_in[4];
  const float* Wh    = (const float*)d_in[5];
  const float* bh    = (const float*)d_in[6];
  const float* gamma = (const float*)d_in[7];

  float* outp = (float*)d_out;
  float* attn_out = outp + (size_t)BATCH * CH * NPIX;   // out | attention

  // ws: fT (2MB) | gT (2MB) | hh (16MB)
  u16* fT = (u16*)d_ws;
  u16* gT = fT + (size_t)BATCH * NPIX * KD;
  u16* hh = gT + (size_t)BATCH * NPIX * KD;

  proj_kernel<<<dim3(BATCH * (NPIX / 32)), dim3(256), 0, stream>>>(
      x, Wf, bf, Wg, bg, Wh, bh, fT, gT, hh);

  fused_attn_pv<<<dim3(BATCH * (NPIX / 64)), dim3(512), 0, stream>>>(
      fT, gT, hh, x, gamma, attn_out, outp);
}